// Round 2
// baseline (6315.116 us; speedup 1.0000x reference)
//
#include <hip/hip_runtime.h>
#include <hip/hip_bf16.h>
#include <hip/hip_cooperative_groups.h>

#define E   512
#define H   1024
#define BB  32
#define TT  512
#define G4  4096            // 4*H
#define NBLK 64             // recurrence blocks; each owns 16 h-columns
// d_out layout: ys [32][512][1024] fp32, then hn [32][1024], then cn [32][1024]
#define YS_ELEMS 16777216

typedef __attribute__((ext_vector_type(8))) short bf16x8;   // 8 bf16 in 4 VGPRs
typedef __attribute__((ext_vector_type(4))) float f32x4;

__device__ __forceinline__ unsigned short f2bf(float x){
    union { float f; unsigned u; } v; v.f = x;
    unsigned r = v.u + 0x7fffu + ((v.u >> 16) & 1u);   // RNE
    return (unsigned short)(r >> 16);
}
__device__ __forceinline__ float bf2f(unsigned short b){
    union { unsigned u; float f; } v; v.u = ((unsigned)b) << 16;
    return v.f;
}
__device__ __forceinline__ float sigm(float x){ return 1.f/(1.f+__expf(-x)); }
__device__ __forceinline__ float tanh_(float x){ return 2.f/(1.f+__expf(-2.f*x)) - 1.f; }

// ---------------- prep: gather+cast A, cast W_ih/W_hh/h0 to bf16; zero flags ----
__global__ void k_prep(const int* __restrict__ ids, const float* __restrict__ emb,
                       const float* __restrict__ Wih, const float* __restrict__ Whh,
                       const float* __restrict__ h0,
                       unsigned short* __restrict__ Abf, unsigned short* __restrict__ Bbf,
                       unsigned short* __restrict__ Wb,  unsigned short* __restrict__ hb,
                       unsigned* __restrict__ flags)
{
    int bx = blockIdx.x, tx = threadIdx.x;
    if (bx == 0) flags[tx] = 0;            // ws is poisoned 0xAA every launch; 256 flags
    const float* src; unsigned short* dst;
    if (bx < 4096) {                       // A gather: m = t*32+b, row = ids[b][t]
        unsigned u = bx*256u + tx;
        int m  = u >> 6;                   // 0..16383
        int e0 = (u & 63) * 8;             // 0..504
        int row = ids[(m & 31) * TT + (m >> 5)];
        src = emb + (size_t)row * E + e0;
        dst = Abf + (size_t)m   * E + e0;
    } else if (bx < 5120) {                // W_ih: 2,097,152 elems
        size_t off = ((size_t)(bx-4096)*256u + tx) * 8;
        src = Wih + off; dst = Bbf + off;
    } else if (bx < 7168) {                // W_hh: 4,194,304 elems
        size_t off = ((size_t)(bx-5120)*256u + tx) * 8;
        src = Whh + off; dst = Wb + off;
    } else {                               // h0: 32,768 elems
        size_t off = ((size_t)(bx-7168)*256u + tx) * 8;
        src = h0 + off; dst = hb + off;
    }
    float4 f0 = *(const float4*)(src);
    float4 f1 = *(const float4*)(src + 4);
    uint4 o;
    o.x = f2bf(f0.x) | ((unsigned)f2bf(f0.y) << 16);
    o.y = f2bf(f0.z) | ((unsigned)f2bf(f0.w) << 16);
    o.z = f2bf(f1.x) | ((unsigned)f2bf(f1.y) << 16);
    o.w = f2bf(f1.z) | ((unsigned)f2bf(f1.w) << 16);
    *(uint4*)dst = o;
}

// ---------------- x_proj GEMM: C[m][n] = sum_k A[m][k]*W_ih[n][k], bf16 out ------
__global__ __launch_bounds__(256) void k_gemm(const unsigned short* __restrict__ A,
        const unsigned short* __restrict__ Bm, unsigned short* __restrict__ C)
{
    __shared__ __align__(16) unsigned short As[128][40];
    __shared__ __align__(16) unsigned short Bs[128][40];
    int tid = threadIdx.x;
    int bm = blockIdx.x & 127;
    int bn = blockIdx.x >> 7;
    int w = tid >> 6, lane = tid & 63, l15 = lane & 15, quad = lane >> 4;
    int wm = w & 1, wn = w >> 1;
    f32x4 acc[4][4] = {};
    for (int kt = 0; kt < 16; ++kt) {
        __syncthreads();
        for (int i = 0; i < 2; ++i) {
            int c = tid + 256*i;
            int row = c >> 2, kc = (c & 3) * 8;
            *(uint4*)&As[row][kc] = *(const uint4*)(A  + ((size_t)(bm*128 + row))*E + kt*32 + kc);
            *(uint4*)&Bs[row][kc] = *(const uint4*)(Bm + ((size_t)(bn*128 + row))*E + kt*32 + kc);
        }
        __syncthreads();
        bf16x8 af[4], bfr[4];
        for (int i = 0; i < 4; ++i) af[i]  = *(const bf16x8*)&As[wm*64 + i*16 + l15][quad*8];
        for (int j = 0; j < 4; ++j) bfr[j] = *(const bf16x8*)&Bs[wn*64 + j*16 + l15][quad*8];
        for (int i = 0; i < 4; ++i)
            for (int j = 0; j < 4; ++j)
                acc[i][j] = __builtin_amdgcn_mfma_f32_16x16x32_bf16(af[i], bfr[j], acc[i][j], 0,0,0);
    }
    for (int i = 0; i < 4; ++i)
        for (int j = 0; j < 4; ++j)
            for (int r = 0; r < 4; ++r) {
                int mg = bm*128 + wm*64 + i*16 + quad*4 + r;
                int ng = bn*128 + wn*64 + j*16 + l15;
                C[(size_t)mg * G4 + ng] = f2bf(acc[i][j][r]);
            }
}

// ---------------- recurrence: 64 blocks x 256 thr, distributed-flag barrier ------
// Block blk owns h-columns blk*16..blk*16+15 (64 W_hh rows, 128KB, LDS-resident).
// Wave w computes gate-group q=w (16 gate rows) over full K=1024, for all 32
// batches: 2 M-tiles x 32 K-steps = 64 MFMAs, A loads pipelined 2-groups-deep
// with counted vmcnt(16) (never 0 mid-loop). Epilogue: all 4 waves, 2 cols per
// lane; each wave publishes its own h slice, drains (vmcnt 0) and raises its
// own flag flags[w*64+blk]. Wave 0 polls all 256 flags (4 per lane).
__global__ __launch_bounds__(256, 1) void k_recur(const unsigned short* __restrict__ xp,
        const unsigned short* __restrict__ Wb, unsigned short* __restrict__ hbuf,
        const float* __restrict__ c0, float* __restrict__ out,
        unsigned* __restrict__ flags)
{
    __shared__ __align__(16) unsigned short Ws[64][1032];  // 64 gate rows x 1024 (+8 pad)
    __shared__ float gbuf[4][32][20];                      // [q][b][local col], +4 pad
    int tid = threadIdx.x;
    int blk = blockIdx.x;
    int w = tid >> 6, lane = tid & 63, l15 = lane & 15, quad = lane >> 4;

    // Load this block's 64 W_hh rows: Ws[n = q*16+kl][k], grow = q*H + blk*16 + kl
    for (int c = 0; c < 32; ++c) {
        int id = tid + 256*c;
        int n = id >> 7, kc = (id & 127) * 8;
        int grow = (n >> 4) * H + blk*16 + (n & 15);
        *(uint4*)&Ws[n][kc] = *(const uint4*)(Wb + (size_t)grow * H + kc);
    }
    // epilogue mapping: every lane owns 2 adjacent h-columns of its wave's quad
    int b   = lane & 31;
    int kp  = lane >> 5;
    int cl0 = w*4 + kp*2;              // local col 0..15
    int kg0 = blk*16 + cl0;            // global h-col
    float2 cc = *(const float2*)(c0 + b*H + kg0);
    float cA = cc.x, cB = cc.y;
    const unsigned short* wrow = &Ws[w*16 + l15][quad*8];
    __syncthreads();

    for (int t = 0; t < TT; ++t) {
        const unsigned short* cur = hbuf + (t & 1) * (BB*H);
        unsigned short*       nxt = hbuf + ((t+1) & 1) * (BB*H);
        // prefetch x_proj[t] (read-only) before the barrier wait
        float xA[4], xB[4];
        #pragma unroll
        for (int q = 0; q < 4; ++q) {
            unsigned x2 = *(const unsigned*)(xp + ((size_t)t*BB + b)*G4 + q*H + kg0);
            xA[q] = bf2f((unsigned short)(x2 & 0xffffu));
            xB[q] = bf2f((unsigned short)(x2 >> 16));
        }
        // ---- barrier: wait until every block has published h(t) (256 flags) ----
        if (tid < 64) {
            unsigned tgt = (unsigned)t;
            const unsigned* fp = flags + lane;
            bool ok;
            do {
                unsigned f0 = __hip_atomic_load(fp,       __ATOMIC_RELAXED, __HIP_MEMORY_SCOPE_AGENT);
                unsigned f1 = __hip_atomic_load(fp + 64,  __ATOMIC_RELAXED, __HIP_MEMORY_SCOPE_AGENT);
                unsigned f2 = __hip_atomic_load(fp + 128, __ATOMIC_RELAXED, __HIP_MEMORY_SCOPE_AGENT);
                unsigned f3 = __hip_atomic_load(fp + 192, __ATOMIC_RELAXED, __HIP_MEMORY_SCOPE_AGENT);
                ok = (f0 >= tgt) & (f1 >= tgt) & (f2 >= tgt) & (f3 >= tgt);
            } while (!__all(ok));
        }
        __syncthreads();   // also drains all waves' vmem (x prefetch, old stores)
        // ---- gates: wave w = gate-group q, full K=1024, 2 M-tiles ----
        f32x4 acc0 = {}, acc1 = {};
        {
            const unsigned short* pa0 = cur + (size_t)l15 * H + quad*8;
            const unsigned short* pa1 = pa0 + 16*H;
            bf16x8 avA[16], avB[16];
#define LDA(d, p, O) asm volatile("global_load_dwordx4 %0, %1, off offset:" O " sc0 sc1" \
                                  : "=v"(d) : "v"(p))
#define ISSUE8(AV, b0, b1) do { \
            LDA(AV[0], b0, "0");   LDA(AV[1], b1, "0");   \
            LDA(AV[2], b0, "64");  LDA(AV[3], b1, "64");  \
            LDA(AV[4], b0, "128"); LDA(AV[5], b1, "128"); \
            LDA(AV[6], b0, "192"); LDA(AV[7], b1, "192"); \
            LDA(AV[8], b0, "256"); LDA(AV[9], b1, "256"); \
            LDA(AV[10],b0, "320"); LDA(AV[11],b1, "320"); \
            LDA(AV[12],b0, "384"); LDA(AV[13],b1, "384"); \
            LDA(AV[14],b0, "448"); LDA(AV[15],b1, "448"); } while(0)
#define MFMA8(AV, G, VN) do { \
            const unsigned short* wp = wrow + (G)*256; \
            bf16x8 bv0 = *(const bf16x8*)(wp + 0*32); \
            bf16x8 bv1 = *(const bf16x8*)(wp + 1*32); \
            bf16x8 bv2 = *(const bf16x8*)(wp + 2*32); \
            bf16x8 bv3 = *(const bf16x8*)(wp + 3*32); \
            bf16x8 bv4 = *(const bf16x8*)(wp + 4*32); \
            bf16x8 bv5 = *(const bf16x8*)(wp + 5*32); \
            bf16x8 bv6 = *(const bf16x8*)(wp + 6*32); \
            bf16x8 bv7 = *(const bf16x8*)(wp + 7*32); \
            asm volatile("s_waitcnt vmcnt(" VN ")" ::: "memory"); \
            __builtin_amdgcn_sched_barrier(0); \
            acc0 = __builtin_amdgcn_mfma_f32_16x16x32_bf16(AV[0],  bv0, acc0, 0,0,0); \
            acc1 = __builtin_amdgcn_mfma_f32_16x16x32_bf16(AV[1],  bv0, acc1, 0,0,0); \
            acc0 = __builtin_amdgcn_mfma_f32_16x16x32_bf16(AV[2],  bv1, acc0, 0,0,0); \
            acc1 = __builtin_amdgcn_mfma_f32_16x16x32_bf16(AV[3],  bv1, acc1, 0,0,0); \
            acc0 = __builtin_amdgcn_mfma_f32_16x16x32_bf16(AV[4],  bv2, acc0, 0,0,0); \
            acc1 = __builtin_amdgcn_mfma_f32_16x16x32_bf16(AV[5],  bv2, acc1, 0,0,0); \
            acc0 = __builtin_amdgcn_mfma_f32_16x16x32_bf16(AV[6],  bv3, acc0, 0,0,0); \
            acc1 = __builtin_amdgcn_mfma_f32_16x16x32_bf16(AV[7],  bv3, acc1, 0,0,0); \
            acc0 = __builtin_amdgcn_mfma_f32_16x16x32_bf16(AV[8],  bv4, acc0, 0,0,0); \
            acc1 = __builtin_amdgcn_mfma_f32_16x16x32_bf16(AV[9],  bv4, acc1, 0,0,0); \
            acc0 = __builtin_amdgcn_mfma_f32_16x16x32_bf16(AV[10], bv5, acc0, 0,0,0); \
            acc1 = __builtin_amdgcn_mfma_f32_16x16x32_bf16(AV[11], bv5, acc1, 0,0,0); \
            acc0 = __builtin_amdgcn_mfma_f32_16x16x32_bf16(AV[12], bv6, acc0, 0,0,0); \
            acc1 = __builtin_amdgcn_mfma_f32_16x16x32_bf16(AV[13], bv6, acc1, 0,0,0); \
            acc0 = __builtin_amdgcn_mfma_f32_16x16x32_bf16(AV[14], bv7, acc0, 0,0,0); \
            acc1 = __builtin_amdgcn_mfma_f32_16x16x32_bf16(AV[15], bv7, acc1, 0,0,0); } while(0)

            ISSUE8(avA, pa0,       pa1);
            ISSUE8(avB, pa0 + 256, pa1 + 256);
            MFMA8(avA, 0, "16");
            ISSUE8(avA, pa0 + 512, pa1 + 512);
            MFMA8(avB, 1, "16");
            ISSUE8(avB, pa0 + 768, pa1 + 768);
            MFMA8(avA, 2, "16");
            MFMA8(avB, 3, "0");
#undef LDA
#undef ISSUE8
#undef MFMA8
        }
        #pragma unroll
        for (int r = 0; r < 4; ++r) {
            gbuf[w][quad*4 + r][l15]      = acc0[r];
            gbuf[w][16 + quad*4 + r][l15] = acc1[r];
        }
        __syncthreads();
        // ---- epilogue: all 4 waves, 2 columns per lane ----
        {
            float pA[4], pB[4];
            #pragma unroll
            for (int q = 0; q < 4; ++q) {
                float2 g2 = *(const float2*)&gbuf[q][b][cl0];
                pA[q] = g2.x + xA[q];
                pB[q] = g2.y + xB[q];
            }
            float iA = sigm(pA[0]), fA = sigm(pA[1]), gA = tanh_(pA[2]), oA = sigm(pA[3]);
            float iB = sigm(pB[0]), fB = sigm(pB[1]), gB = tanh_(pB[2]), oB = sigm(pB[3]);
            cA = fA * cA + iA * gA;
            cB = fB * cB + iB * gB;
            float hA = oA * tanh_(cA);
            float hB = oB * tanh_(cB);
            // 1) publish h(t+1) to the coherence point
            unsigned hp = (unsigned)f2bf(hA) | ((unsigned)f2bf(hB) << 16);
            __hip_atomic_store((unsigned*)(nxt + b*H + kg0), hp,
                               __ATOMIC_RELAXED, __HIP_MEMORY_SCOPE_AGENT);
            // 2) drain this wave's vmem (h stores included), then raise its flag
            asm volatile("s_waitcnt vmcnt(0)" ::: "memory");
            if (lane == 0)
                __hip_atomic_store(&flags[w*64 + blk], (unsigned)(t+1),
                                   __ATOMIC_RELAXED, __HIP_MEMORY_SCOPE_AGENT);
            // 3) off-critical-path output stores
            *(float2*)(out + (size_t)b*(TT*H) + (size_t)t*H + kg0) = make_float2(hA, hB);
            if (t == TT-1) {
                *(float2*)(out + YS_ELEMS + b*H + kg0)         = make_float2(hA, hB);
                *(float2*)(out + YS_ELEMS + 32768 + b*H + kg0) = make_float2(cA, cB);
            }
        }
    }
}

// ---------------- launch --------------------------------------------------------
extern "C" void kernel_launch(void* const* d_in, const int* in_sizes, int n_in,
                              void* d_out, int out_size, void* d_ws, size_t ws_size,
                              hipStream_t stream)
{
    const int*   ids = (const int*)  d_in[0];
    const float* h0  = (const float*)d_in[1];
    const float* c0  = (const float*)d_in[2];
    const float* emb = (const float*)d_in[3];
    const float* Wih = (const float*)d_in[4];
    const float* Whh = (const float*)d_in[5];
    float* out = (float*)d_out;
    char* ws = (char*)d_ws;
    unsigned short* xp  = (unsigned short*)(ws);                          // 134,217,728 B
    unsigned short* Abf = (unsigned short*)(ws + 134217728);              //  16,777,216 B
    unsigned short* Bbf = (unsigned short*)(ws + 134217728 + 16777216);   //   4,194,304 B
    unsigned short* Wb  = (unsigned short*)(ws + 134217728 + 16777216 + 4194304);          // 8,388,608 B
    unsigned short* hb  = (unsigned short*)(ws + 134217728 + 16777216 + 4194304 + 8388608); //  131,072 B
    unsigned*       fl  = (unsigned*)      (ws + 134217728 + 16777216 + 4194304 + 8388608 + 131072); // 1,024 B

    k_prep<<<7184, 256, 0, stream>>>(ids, emb, Wih, Whh, h0, Abf, Bbf, Wb, hb, fl);
    k_gemm<<<4096, 256, 0, stream>>>(Abf, Bbf, xp);
    void* args[] = { (void*)&xp, (void*)&Wb, (void*)&hb, (void*)&c0, (void*)&out, (void*)&fl };
    hipLaunchCooperativeKernel((void*)k_recur, dim3(NBLK), dim3(256), args, 0, stream);
}

// Round 3
// 3474.398 us; speedup vs baseline: 1.8176x; 1.8176x over previous
//
#include <hip/hip_runtime.h>
#include <hip/hip_bf16.h>
#include <hip/hip_cooperative_groups.h>

#define E   512
#define H   1024
#define BB  32
#define TT  512
#define G4  4096            // 4*H
#define NBLK 64             // recurrence blocks; each owns 16 h-columns
// d_out layout: ys [32][512][1024] fp32, then hn [32][1024], then cn [32][1024]
#define YS_ELEMS 16777216

typedef __attribute__((ext_vector_type(8))) short bf16x8;   // 8 bf16 in 4 VGPRs
typedef __attribute__((ext_vector_type(4))) float f32x4;

__device__ __forceinline__ unsigned short f2bf(float x){
    union { float f; unsigned u; } v; v.f = x;
    unsigned r = v.u + 0x7fffu + ((v.u >> 16) & 1u);   // RNE
    return (unsigned short)(r >> 16);
}
__device__ __forceinline__ float bf2f(unsigned short b){
    union { unsigned u; float f; } v; v.u = ((unsigned)b) << 16;
    return v.f;
}
__device__ __forceinline__ float sigm(float x){ return 1.f/(1.f+__expf(-x)); }
__device__ __forceinline__ float tanh_(float x){ return 2.f/(1.f+__expf(-2.f*x)) - 1.f; }

// ---------------- prep: gather+cast A, cast W_ih/W_hh/h0 to bf16; zero flags ----
__global__ void k_prep(const int* __restrict__ ids, const float* __restrict__ emb,
                       const float* __restrict__ Wih, const float* __restrict__ Whh,
                       const float* __restrict__ h0,
                       unsigned short* __restrict__ Abf, unsigned short* __restrict__ Bbf,
                       unsigned short* __restrict__ Wb,  unsigned short* __restrict__ hb,
                       unsigned* __restrict__ flags)
{
    int bx = blockIdx.x, tx = threadIdx.x;
    if (bx == 0) flags[tx] = 0;            // ws is poisoned 0xAA every launch; 256 flags
    const float* src; unsigned short* dst;
    if (bx < 4096) {                       // A gather: m = t*32+b, row = ids[b][t]
        unsigned u = bx*256u + tx;
        int m  = u >> 6;                   // 0..16383
        int e0 = (u & 63) * 8;             // 0..504
        int row = ids[(m & 31) * TT + (m >> 5)];
        src = emb + (size_t)row * E + e0;
        dst = Abf + (size_t)m   * E + e0;
    } else if (bx < 5120) {                // W_ih: 2,097,152 elems
        size_t off = ((size_t)(bx-4096)*256u + tx) * 8;
        src = Wih + off; dst = Bbf + off;
    } else if (bx < 7168) {                // W_hh: 4,194,304 elems
        size_t off = ((size_t)(bx-5120)*256u + tx) * 8;
        src = Whh + off; dst = Wb + off;
    } else {                               // h0: 32,768 elems
        size_t off = ((size_t)(bx-7168)*256u + tx) * 8;
        src = h0 + off; dst = hb + off;
    }
    float4 f0 = *(const float4*)(src);
    float4 f1 = *(const float4*)(src + 4);
    uint4 o;
    o.x = f2bf(f0.x) | ((unsigned)f2bf(f0.y) << 16);
    o.y = f2bf(f0.z) | ((unsigned)f2bf(f0.w) << 16);
    o.z = f2bf(f1.x) | ((unsigned)f2bf(f1.y) << 16);
    o.w = f2bf(f1.z) | ((unsigned)f2bf(f1.w) << 16);
    *(uint4*)dst = o;
}

// ---------------- x_proj GEMM: C[m][n] = sum_k A[m][k]*W_ih[n][k], bf16 out ------
__global__ __launch_bounds__(256) void k_gemm(const unsigned short* __restrict__ A,
        const unsigned short* __restrict__ Bm, unsigned short* __restrict__ C)
{
    __shared__ __align__(16) unsigned short As[128][40];
    __shared__ __align__(16) unsigned short Bs[128][40];
    int tid = threadIdx.x;
    int bm = blockIdx.x & 127;
    int bn = blockIdx.x >> 7;
    int w = tid >> 6, lane = tid & 63, l15 = lane & 15, quad = lane >> 4;
    int wm = w & 1, wn = w >> 1;
    f32x4 acc[4][4] = {};
    for (int kt = 0; kt < 16; ++kt) {
        __syncthreads();
        for (int i = 0; i < 2; ++i) {
            int c = tid + 256*i;
            int row = c >> 2, kc = (c & 3) * 8;
            *(uint4*)&As[row][kc] = *(const uint4*)(A  + ((size_t)(bm*128 + row))*E + kt*32 + kc);
            *(uint4*)&Bs[row][kc] = *(const uint4*)(Bm + ((size_t)(bn*128 + row))*E + kt*32 + kc);
        }
        __syncthreads();
        bf16x8 af[4], bfr[4];
        for (int i = 0; i < 4; ++i) af[i]  = *(const bf16x8*)&As[wm*64 + i*16 + l15][quad*8];
        for (int j = 0; j < 4; ++j) bfr[j] = *(const bf16x8*)&Bs[wn*64 + j*16 + l15][quad*8];
        for (int i = 0; i < 4; ++i)
            for (int j = 0; j < 4; ++j)
                acc[i][j] = __builtin_amdgcn_mfma_f32_16x16x32_bf16(af[i], bfr[j], acc[i][j], 0,0,0);
    }
    for (int i = 0; i < 4; ++i)
        for (int j = 0; j < 4; ++j)
            for (int r = 0; r < 4; ++r) {
                int mg = bm*128 + wm*64 + i*16 + quad*4 + r;
                int ng = bn*128 + wn*64 + j*16 + l15;
                C[(size_t)mg * G4 + ng] = f2bf(acc[i][j][r]);
            }
}

// ---------------- recurrence: 64 blocks x 256 thr ------------------------------
// Block blk owns h-columns blk*16..blk*16+15 (64 gate rows). W_hh slice lives in
// VGPRs (32 bf16x8 per wave, loaded once). Per step: h(t) [32x1024 bf16, 64KB]
// is staged COALESCED into LDS once per block (16 x dwordx4 per thread, sc0 sc1
// for LLC freshness), XOR-swizzled (byte ^= (row&7)<<4) so the MFMA A-fragment
// ds_read_b128s are conflict-free. Wave w computes gate-group w (N=16) over
// full K=1024 from LDS. Epilogue/flags identical to the proven R2 protocol.
__global__ __launch_bounds__(256, 1) void k_recur(const unsigned short* __restrict__ xp,
        const unsigned short* __restrict__ Wb, unsigned short* __restrict__ hbuf,
        const float* __restrict__ c0, float* __restrict__ out,
        unsigned* __restrict__ flags)
{
    __shared__ __align__(16) unsigned short Hs[BB*H];      // 64 KB, swizzled
    __shared__ float gbuf[4][32][20];                      // [q][b][col], padded
    int tid = threadIdx.x;
    int blk = blockIdx.x;
    int w = tid >> 6, lane = tid & 63, l15 = lane & 15, quad = lane >> 4;

    // ---- W_hh preload into VGPRs: wave w = gate group w, N-row = blk*16+l15 ----
    bf16x8 wf[32];
    {
        const unsigned short* wp = Wb + (size_t)(w*H + blk*16 + l15)*H + quad*8;
        #pragma unroll
        for (int k2 = 0; k2 < 32; ++k2)
            wf[k2] = *(const bf16x8*)(wp + k2*32);
    }
    // epilogue mapping: every lane owns 2 adjacent h-columns of its wave's quad
    int b   = lane & 31;
    int kp  = lane >> 5;
    int cl0 = w*4 + kp*2;              // local col 0..15
    int kg0 = blk*16 + cl0;            // global h-col
    float2 cc = *(const float2*)(c0 + b*H + kg0);
    float cA = cc.x, cB = cc.y;

    // ---- stage addressing (precomputed; per-step is pure base+immediate) ----
    unsigned base16 = (unsigned)tid * 16;        // byte pos within a 4KB chunk
    unsigned hi     = base16 >> 11;              // 0/1: which row of the chunk
    unsigned inrow  = base16 & 2047;
    char* dwb[4];                                // ds_write bases, period-4 in i
    #pragma unroll
    for (int j = 0; j < 4; ++j)
        dwb[j] = (char*)Hs + hi*2048 + (inrow ^ ((((unsigned)j*2u + hi) & 7u) << 4));
    const char* g0 = (const char*)hbuf + base16;         // ping buffer
    const char* g1 = g0 + BB*H*2;                        // pong buffer

    // ---- A-fragment ds_read bases (swizzle folded: off(k2) = (k2^xb)*64+low) ----
    unsigned X   = (unsigned)(l15 & 7) << 4;
    unsigned xb  = ((unsigned)l15 >> 2) & 1u;
    unsigned low = ((unsigned)quad * 16u) ^ (X & 48u);
    const char* hsb = (const char*)Hs;
    const char* p0e = hsb + l15*2048 + low + (xb ? 64u : 0u);   // rows 0..15, even k2
    const char* p0o = hsb + l15*2048 + low + (xb ? 0u : 64u);   // rows 0..15, odd  k2
    const char* p1e = p0e + 16*2048;                            // rows 16..31
    const char* p1o = p0o + 16*2048;

    for (int t = 0; t < TT; ++t) {
        // prefetch x_proj[t] (read-only, L2-cacheable) before the barrier wait
        float xA[4], xB[4];
        #pragma unroll
        for (int q = 0; q < 4; ++q) {
            unsigned x2 = *(const unsigned*)(xp + ((size_t)t*BB + b)*G4 + q*H + kg0);
            xA[q] = bf2f((unsigned short)(x2 & 0xffffu));
            xB[q] = bf2f((unsigned short)(x2 >> 16));
        }
        // ---- barrier: wait until every block-wave has published h(t) ----
        if (tid < 64) {
            unsigned tgt = (unsigned)t;
            const unsigned* fp = flags + lane;
            bool ok;
            do {
                unsigned f0 = __hip_atomic_load(fp,       __ATOMIC_RELAXED, __HIP_MEMORY_SCOPE_AGENT);
                unsigned f1 = __hip_atomic_load(fp + 64,  __ATOMIC_RELAXED, __HIP_MEMORY_SCOPE_AGENT);
                unsigned f2 = __hip_atomic_load(fp + 128, __ATOMIC_RELAXED, __HIP_MEMORY_SCOPE_AGENT);
                unsigned f3 = __hip_atomic_load(fp + 192, __ATOMIC_RELAXED, __HIP_MEMORY_SCOPE_AGENT);
                ok = (f0 >= tgt) & (f1 >= tgt) & (f2 >= tgt) & (f3 >= tgt);
            } while (!__all(ok));
        }
        __syncthreads();
        // ---- stage h(t) into LDS, coalesced (16 x 4KB bursts per block) ----
        {
            const char* gsel = (t & 1) ? g1 : g0;
            uint4 sv[16];
            #pragma unroll
            for (int i = 0; i < 16; ++i)
                asm volatile("global_load_dwordx4 %0, %1, off sc0 sc1"
                             : "=v"(sv[i]) : "v"(gsel + (size_t)i*4096));
            asm volatile("s_waitcnt vmcnt(0)" ::: "memory");
            __builtin_amdgcn_sched_barrier(0);
            #pragma unroll
            for (int i = 0; i < 16; ++i)
                *(uint4*)(dwb[i & 3] + i*4096) = sv[i];
        }
        __syncthreads();
        // ---- gates: wave w = gate-group w, full K=1024, 2 M-tiles, 4 chains ----
        f32x4 a0e = {}, a0o = {}, a1e = {}, a1o = {};
        #pragma unroll
        for (int k2 = 0; k2 < 32; k2 += 2) {
            bf16x8 ae0 = *(const bf16x8*)(p0e + k2*64);
            bf16x8 ae1 = *(const bf16x8*)(p1e + k2*64);
            bf16x8 ao0 = *(const bf16x8*)(p0o + k2*64);   // this is k2+1's data
            bf16x8 ao1 = *(const bf16x8*)(p1o + k2*64);
            a0e = __builtin_amdgcn_mfma_f32_16x16x32_bf16(ae0, wf[k2],   a0e, 0,0,0);
            a1e = __builtin_amdgcn_mfma_f32_16x16x32_bf16(ae1, wf[k2],   a1e, 0,0,0);
            a0o = __builtin_amdgcn_mfma_f32_16x16x32_bf16(ao0, wf[k2+1], a0o, 0,0,0);
            a1o = __builtin_amdgcn_mfma_f32_16x16x32_bf16(ao1, wf[k2+1], a1o, 0,0,0);
        }
        f32x4 acc0 = a0e + a0o;
        f32x4 acc1 = a1e + a1o;
        #pragma unroll
        for (int r = 0; r < 4; ++r) {
            gbuf[w][quad*4 + r][l15]      = acc0[r];
            gbuf[w][16 + quad*4 + r][l15] = acc1[r];
        }
        __syncthreads();
        // ---- epilogue: all 4 waves, 2 columns per lane (proven R2 protocol) ----
        {
            const unsigned short* nxt = hbuf + ((t+1) & 1) * (BB*H);
            float pA[4], pB[4];
            #pragma unroll
            for (int q = 0; q < 4; ++q) {
                float2 g2 = *(const float2*)&gbuf[q][b][cl0];
                pA[q] = g2.x + xA[q];
                pB[q] = g2.y + xB[q];
            }
            float iA = sigm(pA[0]), fA = sigm(pA[1]), gA = tanh_(pA[2]), oA = sigm(pA[3]);
            float iB = sigm(pB[0]), fB = sigm(pB[1]), gB = tanh_(pB[2]), oB = sigm(pB[3]);
            cA = fA * cA + iA * gA;
            cB = fB * cB + iB * gB;
            float hA = oA * tanh_(cA);
            float hB = oB * tanh_(cB);
            // 1) publish h(t+1) to the coherence point
            unsigned hp = (unsigned)f2bf(hA) | ((unsigned)f2bf(hB) << 16);
            __hip_atomic_store((unsigned*)(nxt + b*H + kg0), hp,
                               __ATOMIC_RELAXED, __HIP_MEMORY_SCOPE_AGENT);
            // 2) drain this wave's vmem (h stores included), then raise its flag
            asm volatile("s_waitcnt vmcnt(0)" ::: "memory");
            if (lane == 0)
                __hip_atomic_store(&flags[w*64 + blk], (unsigned)(t+1),
                                   __ATOMIC_RELAXED, __HIP_MEMORY_SCOPE_AGENT);
            // 3) off-critical-path output stores
            *(float2*)(out + (size_t)b*(TT*H) + (size_t)t*H + kg0) = make_float2(hA, hB);
            if (t == TT-1) {
                *(float2*)(out + YS_ELEMS + b*H + kg0)         = make_float2(hA, hB);
                *(float2*)(out + YS_ELEMS + 32768 + b*H + kg0) = make_float2(cA, cB);
            }
        }
    }
}

// ---------------- launch --------------------------------------------------------
extern "C" void kernel_launch(void* const* d_in, const int* in_sizes, int n_in,
                              void* d_out, int out_size, void* d_ws, size_t ws_size,
                              hipStream_t stream)
{
    const int*   ids = (const int*)  d_in[0];
    const float* h0  = (const float*)d_in[1];
    const float* c0  = (const float*)d_in[2];
    const float* emb = (const float*)d_in[3];
    const float* Wih = (const float*)d_in[4];
    const float* Whh = (const float*)d_in[5];
    float* out = (float*)d_out;
    char* ws = (char*)d_ws;
    unsigned short* xp  = (unsigned short*)(ws);                          // 134,217,728 B
    unsigned short* Abf = (unsigned short*)(ws + 134217728);              //  16,777,216 B
    unsigned short* Bbf = (unsigned short*)(ws + 134217728 + 16777216);   //   4,194,304 B
    unsigned short* Wb  = (unsigned short*)(ws + 134217728 + 16777216 + 4194304);          // 8,388,608 B
    unsigned short* hb  = (unsigned short*)(ws + 134217728 + 16777216 + 4194304 + 8388608); //  131,072 B
    unsigned*       fl  = (unsigned*)      (ws + 134217728 + 16777216 + 4194304 + 8388608 + 131072); // 1,024 B

    k_prep<<<7184, 256, 0, stream>>>(ids, emb, Wih, Whh, h0, Abf, Bbf, Wb, hb, fl);
    k_gemm<<<4096, 256, 0, stream>>>(Abf, Bbf, xp);
    void* args[] = { (void*)&xp, (void*)&Wb, (void*)&hb, (void*)&c0, (void*)&out, (void*)&fl };
    hipLaunchCooperativeKernel((void*)k_recur, dim3(NBLK), dim3(256), args, 0, stream);
}